// Round 8
// baseline (171.324 us; speedup 1.0000x reference)
//
#include <hip/hip_runtime.h>
#include <hip/hip_bf16.h>

typedef __attribute__((ext_vector_type(4))) int i32x4;
typedef __attribute__((ext_vector_type(8))) int i32x8;
typedef __attribute__((ext_vector_type(16))) float f32x16;

#define GLOBAL_CPTR(x) ((__attribute__((address_space(1))) const void*)(x))
#define LDS_PTR(x)     ((__attribute__((address_space(3))) void*)(x))

// ---------------------------------------------------------------------------
// MXFP4 quantize: fp32 -> packed E2M1 nibbles + E8M0 scale bytes.
// One thread = one full 32-elem MXFP block (no cross-lane reduce).
// Wave = 64 consecutive rows of ONE k-chunk -> 1KB contiguous data stores.
// Data layout (16B chunks, chunk-major for conflict-free GEMM LDS reads):
//   chunk = (row>>8)*(K/32) + (k>>5); data = chunk*4096 + (row&255)*16
// Scale layout: byte = chunk*256 + (row&31)*8 + ((row>>5)&7)
// ---------------------------------------------------------------------------
__global__ __launch_bounds__(256) void mxfp4_quant_pack_kernel(
    const float* __restrict__ in, unsigned char* __restrict__ outq,
    unsigned char* __restrict__ outsc, int kshift) {
  const int KC = 1 << (kshift - 5);
  const int bid = blockIdx.x;
  const int kc = bid & (KC - 1);      // k-chunk
  const int rp = bid >> (kshift - 5); // 256-row panel
  const int r  = threadIdx.x;        // row within panel
  const long long row = ((long long)rp << 8) + r;
  const float* src = in + (row << kshift) + (kc << 5);

  float v[32];
#pragma unroll
  for (int i = 0; i < 8; ++i)
    *reinterpret_cast<float4*>(v + 4 * i) =
        *reinterpret_cast<const float4*>(src + 4 * i);

  float am = 0.f;
#pragma unroll
  for (int j = 0; j < 32; ++j) am = fmaxf(am, fabsf(v[j]));

  float safe = am > 0.f ? am : 1.f;
  int se = ilogbf(safe) - 2;           // floor(log2(amax)) - E2M1_EMAX
  float inv = ldexpf(1.f, -se);

  unsigned int packs[4] = {0, 0, 0, 0};
#pragma unroll
  for (int j = 0; j < 32; ++j) {
    float val = v[j] * inv;                  // exact (power-of-2)
    float av = fabsf(val);
    float avc = fmaxf(av, 9.765625e-4f);     // 2^-10 floor
    int ee = (int)((__float_as_uint(avc) >> 23) & 0xFF) - 127;  // floor(log2)
    ee = ee < 0 ? 0 : (ee > 2 ? 2 : ee);
    float step  = ldexpf(1.f, ee - 1);
    float istep = ldexpf(1.f, 1 - ee);
    float q = rintf(av * istep) * step;      // round-half-to-even, exact grid
    q = fminf(q, 6.f);
    // E2M1 code: {0,0.5,1,1.5,2,3,4,6} -> 0..7
    unsigned int c = q >= 5.f   ? 7u
                   : q >= 3.5f  ? 6u
                   : q >= 2.5f  ? 5u
                   : q >= 1.75f ? 4u
                   : q >= 1.25f ? 3u
                   : q >= 0.75f ? 2u
                   : q >= 0.25f ? 1u : 0u;
    if (val < 0.f) c |= 8u;                  // sign bit
    packs[j >> 3] |= c << (4 * (j & 7));
  }

  const size_t chunk = (size_t)rp * KC + kc;
  *reinterpret_cast<uint4*>(outq + chunk * 4096 + (size_t)r * 16) =
      make_uint4(packs[0], packs[1], packs[2], packs[3]);
  outsc[chunk * 256 + (r & 31) * 8 + (r >> 5)] = (unsigned char)(se + 127);
}

// ---------------------------------------------------------------------------
// MX-FP4 scaled GEMM: C[M][N] = dequant(A)*dequant(B)^T + bias
// via v_mfma_scale_f32_32x32x64_f8f6f4 (FMT=4 E2M1, E8M0 block scales).
// BM=128, BN=256, BK=128, 8 waves (2Mx4N, 64x64 out/wave -> acc 2x2 f32x16 =
// 64 regs), __launch_bounds__(512,4) -> <=128 regs -> 2 WGs/CU resident:
// independent WGs overlap each other's barrier/vmcnt stalls (R6/R7 were
// latency-bound at 1 WG/CU: MfmaUtil 33%, VALU 30%, Occ 19%).
// LDS/buf 26624B: [A 4chx2048][B 4chx4096 @8192][Asc 4x256 @24576]
//                 [Bsc 4x256 @25600]; dbuf = 52KB.
// Uniform 4 DMA loads/wave/K-tile; 1 barrier per K-tile.
// ---------------------------------------------------------------------------
#define BM 128
#define BN 256
#define NTHR 512
#define BUFS 26624

__global__ __launch_bounds__(NTHR, 4) void mxfp_gemm_kernel(
    const unsigned char* __restrict__ Aq, const unsigned char* __restrict__ Asc,
    const unsigned char* __restrict__ Bq, const unsigned char* __restrict__ Bsc,
    const float* __restrict__ bias, float* __restrict__ C,
    int M, int N, int K) {
  __shared__ unsigned char lds[2 * BUFS];  // 52 KiB

  const int tid = threadIdx.x;
  const int l   = tid & 63;
  const int wid = tid >> 6;
  const int wm  = wid >> 2;  // 0..1 (64-row half)
  const int wn  = wid & 3;   // 0..3 (64-col quarter)

  const int nwg = gridDim.x;       // 1024, multiple of 8
  const int bid = blockIdx.x;
  const int swz = (bid & 7) * (nwg >> 3) + (bid >> 3);
  const int nbn = N / BN;          // 16
  const int bm  = swz / nbn;       // 0..63 (128-row panel)
  const int bn  = swz % nbn;

  const int KC = K >> 5;  // 16B-chunks per row

  f32x16 acc[2][2] = {};

// stage one K-tile (4 k-chunks): waves 0-3: 2 B-data + 2 A-data loads;
// waves 4-7: 2 B-data + 2 scale loads.  4 loads per wave, uniform.
#define STAGE(BUFO, KT)                                                        \
  do {                                                                         \
    const size_t kcb = (size_t)(KT) * 4;                                       \
    _Pragma("unroll") for (int jj = 0; jj < 2; ++jj) {                         \
      const int jb = wid * 2 + jj;                                             \
      const int cb = jb >> 2, qb = jb & 3;                                     \
      __builtin_amdgcn_global_load_lds(                                        \
          GLOBAL_CPTR(Bq + (((size_t)bn * KC + kcb + cb) << 12) +              \
                      (qb << 10) + (l << 4)),                                  \
          LDS_PTR(lds + (BUFO) + 8192 + cb * 4096 + qb * 1024), 16, 0, 0);     \
    }                                                                          \
    if (wid < 4) {                                                             \
      _Pragma("unroll") for (int jj = 0; jj < 2; ++jj) {                       \
        const int ja = wid * 2 + jj;                                           \
        const int ca = ja >> 1, ha = ja & 1;                                   \
        __builtin_amdgcn_global_load_lds(                                      \
            GLOBAL_CPTR(Aq + (((size_t)(bm >> 1) * KC + kcb + ca) << 12) +     \
                        ((bm & 1) << 11) + (ha << 10) + (l << 4)),             \
            LDS_PTR(lds + (BUFO) + ca * 2048 + ha * 1024), 16, 0, 0);          \
      }                                                                        \
    } else {                                                                   \
      const int cs = wid - 4;                                                  \
      __builtin_amdgcn_global_load_lds(                                        \
          GLOBAL_CPTR(Asc + (((size_t)(bm >> 1) * KC + kcb + cs) << 8) +       \
                      (l << 2)),                                               \
          LDS_PTR(lds + (BUFO) + 24576 + cs * 256), 4, 0, 0);                  \
      __builtin_amdgcn_global_load_lds(                                        \
          GLOBAL_CPTR(Bsc + (((size_t)bn * KC + kcb + cs) << 8) + (l << 2)),   \
          LDS_PTR(lds + (BUFO) + 25600 + cs * 256), 4, 0, 0);                  \
    }                                                                          \
  } while (0)

// compute one K-tile: per ks-half, 4 frag reads + 2 scale b32 reads, 4 MFMA.
#define KTILE(BUFO)                                                            \
  do {                                                                         \
    const i32x4 z4 = {0, 0, 0, 0};                                             \
    _Pragma("unroll") for (int ks = 0; ks < 2; ++ks) {                         \
      const int cc = (ks << 1) + (l >> 5); /* k-chunk 0..3, lane-split */      \
      i32x8 a8[2], b8[2];                                                      \
      int sa[2], sb[2];                                                        \
      _Pragma("unroll") for (int mb = 0; mb < 2; ++mb)                         \
        a8[mb] = __builtin_shufflevector(                                      \
            *(const i32x4*)(lds + (BUFO) + cc * 2048 +                         \
                            ((wm * 64 + mb * 32 + (l & 31)) << 4)),            \
            z4, 0, 1, 2, 3, 4, 5, 6, 7);                                       \
      _Pragma("unroll") for (int nb = 0; nb < 2; ++nb)                         \
        b8[nb] = __builtin_shufflevector(                                      \
            *(const i32x4*)(lds + (BUFO) + 8192 + cc * 4096 +                  \
                            ((wn * 64 + nb * 32 + (l & 31)) << 4)),            \
            z4, 0, 1, 2, 3, 4, 5, 6, 7);                                       \
      const int av = *(const int*)(lds + (BUFO) + 24576 + cc * 256 +           \
                                   ((l & 31) << 3) + ((bm & 1) << 2));         \
      const int bv = *(const int*)(lds + (BUFO) + 25600 + cc * 256 +           \
                                   ((l & 31) << 3) + ((wn >> 1) << 2));        \
      _Pragma("unroll") for (int mb = 0; mb < 2; ++mb)                         \
        sa[mb] = (int)((unsigned)((av >> (((wm << 1) + mb) << 3)) & 255) *     \
                       0x01010101u);                                           \
      _Pragma("unroll") for (int nb = 0; nb < 2; ++nb)                         \
        sb[nb] = (int)((unsigned)((bv >> ((((wn & 1) << 1) + nb) << 3)) & 255) \
                       * 0x01010101u);                                         \
      _Pragma("unroll") for (int mb = 0; mb < 2; ++mb)                         \
        _Pragma("unroll") for (int nb = 0; nb < 2; ++nb)                       \
          acc[mb][nb] = __builtin_amdgcn_mfma_scale_f32_32x32x64_f8f6f4(       \
              a8[mb], b8[nb], acc[mb][nb], 4, 4, 0, sa[mb], 0, sb[nb]);        \
    }                                                                          \
  } while (0)

  // prologue: tile0 -> buf0
  STAGE(0, 0);
  asm volatile("s_waitcnt vmcnt(0)" ::: "memory");
  __builtin_amdgcn_s_barrier();
  asm volatile("" ::: "memory");

  const int NKT = K >> 7;  // 128-wide K-tiles
  for (int t = 0; t < NKT; ++t) {
    const int tn = (t + 1 < NKT) ? (t + 1) : t;  // clamp -> dead buffer
    const int bufC = (t & 1) ? BUFS : 0;
    const int bufN = (t & 1) ? 0 : BUFS;
    STAGE(bufN, tn);       // issued first: full compute window to land
    KTILE(bufC);
    asm volatile("s_waitcnt vmcnt(0)" ::: "memory");  // 4 loads/wave
    __builtin_amdgcn_s_barrier();
    asm volatile("" ::: "memory");
  }

  // epilogue: 32x32 C/D layout: col=lane&31, row=(reg&3)+8*(reg>>2)+4*(l>>5)
  const int colb = bn * BN + wn * 64 + (l & 31);
  const int rowb = bm * BM + wm * 64 + ((l >> 5) << 2);
#pragma unroll
  for (int mb = 0; mb < 2; ++mb) {
#pragma unroll
    for (int nb = 0; nb < 2; ++nb) {
      const int col = colb + nb * 32;
      const float bv = bias[col];
#pragma unroll
      for (int r = 0; r < 16; ++r) {
        const int row = rowb + mb * 32 + ((r >> 2) << 3) + (r & 3);
        C[(size_t)row * N + col] = acc[mb][nb][r] + bv;
      }
    }
  }
}

// ---------------------------------------------------------------------------
extern "C" void kernel_launch(void* const* d_in, const int* in_sizes, int n_in,
                              void* d_out, int out_size, void* d_ws, size_t ws_size,
                              hipStream_t stream) {
  const float* x    = (const float*)d_in[0];  // [B,S,K] = [M,K]
  const float* w    = (const float*)d_in[1];  // [N,K]
  const float* bias = (const float*)d_in[2];  // [N]
  float* out = (float*)d_out;

  const int N = in_sizes[2];
  const int K = in_sizes[1] / N;
  const int M = (int)((long long)in_sizes[0] / K);
  const int kshift = __builtin_ctz(K);

  unsigned char* xq  = (unsigned char*)d_ws;               // M*K/2
  unsigned char* wq  = xq + ((size_t)M * K >> 1);          // N*K/2
  unsigned char* xsc = wq + ((size_t)N * K >> 1);          // M*K/32
  unsigned char* wsc = xsc + ((size_t)M * K >> 5);         // N*K/32

  const long long nx = (long long)M * K;
  const long long nw = (long long)N * K;

  mxfp4_quant_pack_kernel<<<dim3((unsigned)(nx / 8192)), dim3(256), 0, stream>>>(
      x, xq, xsc, kshift);
  mxfp4_quant_pack_kernel<<<dim3((unsigned)(nw / 8192)), dim3(256), 0, stream>>>(
      w, wq, wsc, kshift);

  dim3 grid((M / BM) * (N / BN));
  mxfp_gemm_kernel<<<grid, dim3(NTHR), 0, stream>>>(xq, xsc, wq, wsc, bias, out,
                                                    M, N, K);
}

// Round 9
// 153.732 us; speedup vs baseline: 1.1144x; 1.1144x over previous
//
#include <hip/hip_runtime.h>
#include <hip/hip_bf16.h>

typedef __attribute__((ext_vector_type(4))) int i32x4;
typedef __attribute__((ext_vector_type(8))) int i32x8;
typedef __attribute__((ext_vector_type(16))) float f32x16;

#define GLOBAL_CPTR(x) ((__attribute__((address_space(1))) const void*)(x))
#define LDS_PTR(x)     ((__attribute__((address_space(3))) void*)(x))

// ---------------------------------------------------------------------------
// MXFP4 quantize: fp32 -> packed E2M1 nibbles + E8M0 scale bytes.
// One 32-elem block per 4-lane group; 8 floats per lane (R7 version — best).
// Data layout (16B chunks, chunk-major for conflict-free GEMM LDS reads):
//   chunk = (row>>8)*(K/32) + (k>>5); data byte = chunk*4096 + (row&255)*16
//           + ((k&31)>>1)
// Scale layout: byte = chunk*256 + (row&31)*8 + ((row>>5)&7)
// ---------------------------------------------------------------------------
__global__ __launch_bounds__(256) void mxfp4_quant_pack_kernel(
    const float* __restrict__ in, unsigned char* __restrict__ outq,
    unsigned char* __restrict__ outsc, int kshift, long long n) {
  long long e = ((long long)blockIdx.x * 256 + threadIdx.x) * 8;
  if (e >= n) return;

  float4 v0 = *reinterpret_cast<const float4*>(in + e);
  float4 v1 = *reinterpret_cast<const float4*>(in + e + 4);
  float vv[8] = {v0.x, v0.y, v0.z, v0.w, v1.x, v1.y, v1.z, v1.w};
  float am = 0.f;
#pragma unroll
  for (int j = 0; j < 8; ++j) am = fmaxf(am, fabsf(vv[j]));
  am = fmaxf(am, __shfl_xor(am, 1, 64));
  am = fmaxf(am, __shfl_xor(am, 2, 64));  // 4 lanes x 8 = 32-elem block

  float safe = am > 0.f ? am : 1.f;
  int se = ilogbf(safe) - 2;           // floor(log2(amax)) - E2M1_EMAX
  float inv = ldexpf(1.f, -se);

  unsigned int pack = 0;
#pragma unroll
  for (int j = 0; j < 8; ++j) {
    float val = vv[j] * inv;                 // exact (power-of-2)
    float av = fabsf(val);
    float avc = fmaxf(av, 9.765625e-4f);     // 2^-10 floor
    int ee = (int)((__float_as_uint(avc) >> 23) & 0xFF) - 127;  // floor(log2)
    ee = ee < 0 ? 0 : (ee > 2 ? 2 : ee);
    float step  = ldexpf(1.f, ee - 1);
    float istep = ldexpf(1.f, 1 - ee);
    float q = rintf(av * istep) * step;      // round-half-to-even, exact grid
    q = fminf(q, 6.f);
    // E2M1 code: {0,0.5,1,1.5,2,3,4,6} -> 0..7
    unsigned int c = q >= 5.f   ? 7u
                   : q >= 3.5f  ? 6u
                   : q >= 2.5f  ? 5u
                   : q >= 1.75f ? 4u
                   : q >= 1.25f ? 3u
                   : q >= 0.75f ? 2u
                   : q >= 0.25f ? 1u : 0u;
    if (val < 0.f) c |= 8u;                  // sign bit
    pack |= c << (4 * j);
  }

  const int row = (int)(e >> kshift);
  const int k = (int)(e & ((1 << kshift) - 1));
  const size_t chunk = (size_t)(row >> 8) * (size_t)(1 << (kshift - 5)) + (k >> 5);
  *(unsigned int*)(outq + chunk * 4096 + (size_t)(row & 255) * 16 +
                   ((k & 31) >> 1)) = pack;
  if ((threadIdx.x & 3) == 0) {
    outsc[chunk * 256 + (row & 31) * 8 + ((row >> 5) & 7)] =
        (unsigned char)(se + 127);
  }
}

// ---------------------------------------------------------------------------
// MX-FP4 scaled GEMM: C[M][N] = dequant(A)*dequant(B)^T + bias
// via v_mfma_scale_f32_32x32x64_f8f6f4 (FMT=4 E2M1, E8M0 block scales).
// 256x256 tile, BK=128, 8 waves (2Mx4N, 128x64 out/wave).
// R9: TRIPLE-buffered LDS (102KB) + counted vmcnt(5) (waits loads issued TWO
// K-tiles ago; just-issued 5 stay in flight across the barrier -- T4) +
// setprio around MFMA clusters (T5: barrier-free K-tile window gives waves
// role diversity to arbitrate).  Data layout identical to R6/R7 (absmax 0).
// LDS buffer: [A data 16KB][B data 16KB][A sc 1KB][B sc 1KB] stride 34816.
// ---------------------------------------------------------------------------
#define BM 256
#define BN 256
#define NTHR 512
#define BUFS 34816

__global__ __launch_bounds__(NTHR, 2) void mxfp_gemm_kernel(
    const unsigned char* __restrict__ Aq, const unsigned char* __restrict__ Asc,
    const unsigned char* __restrict__ Bq, const unsigned char* __restrict__ Bsc,
    const float* __restrict__ bias, float* __restrict__ C,
    int M, int N, int K) {
  __shared__ unsigned char lds[3 * BUFS];  // 102 KiB

  const int tid = threadIdx.x;
  const int l   = tid & 63;
  const int wid = tid >> 6;
  const int wm  = wid >> 2;  // 0..1
  const int wn  = wid & 3;   // 0..3

  const int nwg = gridDim.x;       // multiple of 8
  const int bid = blockIdx.x;
  const int swz = (bid & 7) * (nwg >> 3) + (bid >> 3);
  const int nbn = N / BN;
  const int bm  = swz / nbn;
  const int bn  = swz % nbn;

  const int KC = K >> 5;  // 16B-chunks per row within a panel

  f32x16 acc[4][2] = {};

// stage one K-tile (BKT=128): per wave 2 A-data + 2 B-data + 1 scale = 5 loads.
#define STAGE(BUFO, KT)                                                        \
  do {                                                                         \
    const int cl = wid & 3;                                                    \
    const int rg2 = (wid >> 2) << 1;                                           \
    const size_t abase = ((size_t)bm * KC + (size_t)(KT) * 4 + cl) * 4096;     \
    const size_t bbase = ((size_t)bn * KC + (size_t)(KT) * 4 + cl) * 4096;     \
    _Pragma("unroll") for (int i = 0; i < 2; ++i) {                            \
      __builtin_amdgcn_global_load_lds(                                        \
          GLOBAL_CPTR(Aq + abase + (rg2 + i) * 1024 + (l << 4)),               \
          LDS_PTR(lds + (BUFO) + cl * 4096 + (rg2 + i) * 1024), 16, 0, 0);     \
      __builtin_amdgcn_global_load_lds(                                        \
          GLOBAL_CPTR(Bq + bbase + (rg2 + i) * 1024 + (l << 4)),               \
          LDS_PTR(lds + (BUFO) + 16384 + cl * 4096 + (rg2 + i) * 1024),        \
          16, 0, 0);                                                           \
    }                                                                          \
    if (wid < 4) {                                                             \
      __builtin_amdgcn_global_load_lds(                                        \
          GLOBAL_CPTR(Asc + ((size_t)bm * KC + (size_t)(KT) * 4 + wid) * 256   \
                      + (l << 2)),                                             \
          LDS_PTR(lds + (BUFO) + 32768 + wid * 256), 4, 0, 0);                 \
    } else {                                                                   \
      __builtin_amdgcn_global_load_lds(                                        \
          GLOBAL_CPTR(Bsc + ((size_t)bn * KC + (size_t)(KT) * 4 + (wid - 4))   \
                      * 256 + (l << 2)),                                       \
          LDS_PTR(lds + (BUFO) + 33792 + (wid - 4) * 256), 4, 0, 0);           \
    }                                                                          \
  } while (0)

// compute one K-tile from buffer BUFO: per ks-half, build 6 operand tuples
// + 6 replicated scales, then 8 MFMA (setprio-wrapped).
#define KTILE(BUFO)                                                            \
  do {                                                                         \
    const i32x4 z4 = {0, 0, 0, 0};                                             \
    _Pragma("unroll") for (int ks = 0; ks < 2; ++ks) {                         \
      const int cofs = (ks << 13) + ((l & 32) << 7); /* (2ks+(l>>5))*4096 */   \
      i32x8 a8[4], b8[2];                                                      \
      int sa[4], sb[2];                                                        \
      _Pragma("unroll") for (int mb = 0; mb < 4; ++mb)                         \
        a8[mb] = __builtin_shufflevector(                                      \
            *(const i32x4*)(lds + (BUFO) + cofs +                              \
                            (((wm << 7) + (mb << 5) + (l & 31)) << 4)),        \
            z4, 0, 1, 2, 3, 4, 5, 6, 7);                                       \
      _Pragma("unroll") for (int nb = 0; nb < 2; ++nb)                         \
        b8[nb] = __builtin_shufflevector(                                      \
            *(const i32x4*)(lds + (BUFO) + 16384 + cofs +                      \
                            (((wn << 6) + (nb << 5) + (l & 31)) << 4)),        \
            z4, 0, 1, 2, 3, 4, 5, 6, 7);                                       \
      const int av = *(const int*)(lds + (BUFO) + 32768 + (cofs >> 4) +        \
                                   ((l & 31) << 3) + (wm << 2));               \
      const int bv = *(const ushort*)(lds + (BUFO) + 33792 + (cofs >> 4) +     \
                                      ((l & 31) << 3) + (wn << 1));            \
      _Pragma("unroll") for (int mb = 0; mb < 4; ++mb)                         \
        sa[mb] = (int)((unsigned)((av >> (mb << 3)) & 255) * 0x01010101u);     \
      _Pragma("unroll") for (int nb = 0; nb < 2; ++nb)                         \
        sb[nb] = (int)((unsigned)((bv >> (nb << 3)) & 255) * 0x01010101u);     \
      __builtin_amdgcn_s_setprio(1);                                           \
      _Pragma("unroll") for (int mb = 0; mb < 4; ++mb)                         \
        _Pragma("unroll") for (int nb = 0; nb < 2; ++nb)                       \
          acc[mb][nb] = __builtin_amdgcn_mfma_scale_f32_32x32x64_f8f6f4(       \
              a8[mb], b8[nb], acc[mb][nb], 4, 4, 0, sa[mb], 0, sb[nb]);        \
      __builtin_amdgcn_s_setprio(0);                                           \
    }                                                                          \
  } while (0)

  const int NKT = K >> 7;  // 128-wide K-tiles

  // prologue: tiles 0,1 -> buf0,buf1 (10 loads); vmcnt(5) waits tile0 only.
  STAGE(0, 0);
  STAGE(BUFS, (1 < NKT) ? 1 : 0);
  asm volatile("s_waitcnt vmcnt(5)" ::: "memory");
  __builtin_amdgcn_s_barrier();
  asm volatile("" ::: "memory");

  int bufC = 0, bufN = BUFS, bufP = 2 * BUFS;
  for (int t = 0; t < NKT; ++t) {
    const int tn = (t + 2 < NKT) ? (t + 2) : (NKT - 1);  // clamp -> dead stage
    STAGE(bufP, tn);   // prefetch 2 tiles ahead
    KTILE(bufC);
    // counted: waits the STAGE issued TWO iters ago (tile t+1); the 5 loads
    // just issued stay in flight across the barrier.
    asm volatile("s_waitcnt vmcnt(5)" ::: "memory");
    __builtin_amdgcn_s_barrier();
    asm volatile("" ::: "memory");
    const int tmp = bufC; bufC = bufN; bufN = bufP; bufP = tmp;
  }
  asm volatile("s_waitcnt vmcnt(0)" ::: "memory");  // drain dead tail stages

  // epilogue: 32x32 C/D layout: col=lane&31, row=(reg&3)+8*(reg>>2)+4*(l>>5)
  const int colb = bn * BN + wn * 64 + (l & 31);
  const int rowb = bm * BM + wm * 128 + ((l >> 5) << 2);
  const float bv0 = bias[colb];
  const float bv1 = bias[colb + 32];
#pragma unroll
  for (int mb = 0; mb < 4; ++mb) {
#pragma unroll
    for (int nb = 0; nb < 2; ++nb) {
      const float bv = nb ? bv1 : bv0;
      const int col = colb + nb * 32;
#pragma unroll
      for (int r = 0; r < 16; ++r) {
        const int row = rowb + mb * 32 + ((r >> 2) << 3) + (r & 3);
        C[(size_t)row * N + col] = acc[mb][nb][r] + bv;
      }
    }
  }
}

// ---------------------------------------------------------------------------
extern "C" void kernel_launch(void* const* d_in, const int* in_sizes, int n_in,
                              void* d_out, int out_size, void* d_ws, size_t ws_size,
                              hipStream_t stream) {
  const float* x    = (const float*)d_in[0];  // [B,S,K] = [M,K]
  const float* w    = (const float*)d_in[1];  // [N,K]
  const float* bias = (const float*)d_in[2];  // [N]
  float* out = (float*)d_out;

  const int N = in_sizes[2];
  const int K = in_sizes[1] / N;
  const int M = (int)((long long)in_sizes[0] / K);
  const int kshift = __builtin_ctz(K);

  unsigned char* xq  = (unsigned char*)d_ws;               // M*K/2
  unsigned char* wq  = xq + ((size_t)M * K >> 1);          // N*K/2
  unsigned char* xsc = wq + ((size_t)N * K >> 1);          // M*K/32
  unsigned char* wsc = xsc + ((size_t)M * K >> 5);         // N*K/32

  const long long nx = (long long)M * K;
  const long long nw = (long long)N * K;

  mxfp4_quant_pack_kernel<<<dim3((unsigned)(nx / 2048)), dim3(256), 0, stream>>>(
      x, xq, xsc, kshift, nx);
  mxfp4_quant_pack_kernel<<<dim3((unsigned)(nw / 2048)), dim3(256), 0, stream>>>(
      w, wq, wsc, kshift, nw);

  dim3 grid((M / BM) * (N / BN));
  mxfp_gemm_kernel<<<grid, dim3(NTHR), 0, stream>>>(xq, xsc, wq, wsc, bias, out,
                                                    M, N, K);
}

// Round 10
// 140.158 us; speedup vs baseline: 1.2224x; 1.0968x over previous
//
#include <hip/hip_runtime.h>
#include <hip/hip_bf16.h>

typedef __attribute__((ext_vector_type(4))) int i32x4;
typedef __attribute__((ext_vector_type(8))) int i32x8;
typedef __attribute__((ext_vector_type(16))) float f32x16;

#define GLOBAL_CPTR(x) ((__attribute__((address_space(1))) const void*)(x))
#define LDS_PTR(x)     ((__attribute__((address_space(3))) void*)(x))

// ---------------------------------------------------------------------------
// MXFP4 quantize: fp32 -> packed E2M1 nibbles + E8M0 scale bytes.
// Block = 64 rows x 128 k. Phase 1: coalesced float4 loads (512B bursts/row)
// into padded LDS. Phase 2: one thread = one full 32-elem MXFP block; lanes
// 0-3 of each quad write rows r..r+3 of one chunk = ONE FULL 64B line (kills
// the partial-line RMW amplification of the old layout-scattered stores).
// Data layout (unchanged): chunk=(row>>8)*(K/32)+(k>>5);
//   data = chunk*4096 + (row&255)*16 ; scale = chunk*256+(row&31)*8+(row>>5&7)
// E2M1 encode: code = min(rint(av*2^(1-e)) + 2e, 7)  (e = clamped binade),
// verified identical to the reference round-half-even grid quantization.
// ---------------------------------------------------------------------------
__global__ __launch_bounds__(256) void mxfp4_quant_pack_kernel(
    const float* __restrict__ in, unsigned char* __restrict__ outq,
    unsigned char* __restrict__ outsc, int kshift) {
  const int KC = 1 << (kshift - 5);   // 32-elem chunks per row
  const int CQ = KC >> 2;             // chunk-quads per row (pow2)
  const int bid = blockIdx.x;
  const int cq  = bid & (CQ - 1);     // 128-k span
  const int R   = (bid >> (kshift - 7)) << 6;  // 64-row block base
  const int t   = threadIdx.x;

  __shared__ float sf[64 * 132];      // 33 KB, row stride 132 (pad 4)

  // phase 1: load 64 rows x 128 floats, 512B contiguous per 32-lane group
  const float* base = in + ((size_t)R << kshift) + (cq << 7);
#pragma unroll
  for (int i = 0; i < 8; ++i) {
    const int g   = i * 256 + t;      // float4 index 0..2047
    const int row = g >> 5;           // 32 float4 per row
    const int c4  = g & 31;
    float4 v = *reinterpret_cast<const float4*>(
        base + ((size_t)row << kshift) + (c4 << 2));
    *reinterpret_cast<float4*>(sf + row * 132 + (c4 << 2)) = v;
  }
  __syncthreads();

  // phase 2: thread -> (row rl, chunk kc); quads of threads share kc with
  // 4 consecutive rows (full-line stores).
  const int rl = (t & 3) + ((t >> 4) << 2);   // 0..63
  const int kc = (t >> 2) & 3;                // 0..3
  const float* src = sf + rl * 132 + (kc << 5);
  float v[32];
#pragma unroll
  for (int i = 0; i < 8; ++i)
    *reinterpret_cast<float4*>(v + 4 * i) =
        *reinterpret_cast<const float4*>(src + 4 * i);

  float am = 0.f;
#pragma unroll
  for (int j = 0; j < 32; ++j) am = fmaxf(am, fabsf(v[j]));

  const float safe = am > 0.f ? am : 1.f;
  const int se = ilogbf(safe) - 2;    // floor(log2(amax)) - E2M1_EMAX
  const float inv = ldexpf(1.f, -se);

  unsigned int packs[4] = {0, 0, 0, 0};
#pragma unroll
  for (int j = 0; j < 32; ++j) {
    const float val = v[j] * inv;              // exact (power-of-2)
    const float av = fabsf(val);
    const float avc = fmaxf(av, 9.765625e-4f); // 2^-10 floor
    int ee = (int)((__float_as_uint(avc) >> 23) & 0xFF) - 127;
    ee = ee < 0 ? 0 : (ee > 2 ? 2 : ee);
    const float istep = __uint_as_float((unsigned)(128 - ee) << 23); // 2^(1-ee)
    const int m = (int)rintf(av * istep);      // exact small int
    unsigned int c = (unsigned)(m + (ee << 1));
    c = c > 7u ? 7u : c;
    c |= (__float_as_uint(val) >> 28) & 8u;    // sign bit -> bit3
    packs[j >> 3] |= c << (4 * (j & 7));
  }

  const int row = R + rl;
  const size_t chunk = (size_t)(row >> 8) * KC + (cq << 2) + kc;
  *reinterpret_cast<uint4*>(outq + chunk * 4096 + (size_t)(row & 255) * 16) =
      make_uint4(packs[0], packs[1], packs[2], packs[3]);
  outsc[chunk * 256 + (row & 31) * 8 + ((row >> 5) & 7)] =
      (unsigned char)(se + 127);
}

// ---------------------------------------------------------------------------
// MX-FP4 scaled GEMM (R7 verbatim -- best measured: 88.0 us, absmax 0):
// C[M][N] = dequant(A)*dequant(B)^T + bias via mfma_scale_f32_32x32x64_f8f6f4.
// 256x256 tile, BK=128, 8 waves (2Mx4N, 128x64 out/wave), dbuf LDS (68KB),
// chunk-major LDS layout, 1 barrier per K-tile, 5 DMA loads/wave/K-tile.
// LDS buffer: [A data 16KB][B data 16KB][A sc 1KB][B sc 1KB] stride 34816.
// ---------------------------------------------------------------------------
#define BM 256
#define BN 256
#define NTHR 512
#define BUFS 34816

__global__ __launch_bounds__(NTHR, 2) void mxfp_gemm_kernel(
    const unsigned char* __restrict__ Aq, const unsigned char* __restrict__ Asc,
    const unsigned char* __restrict__ Bq, const unsigned char* __restrict__ Bsc,
    const float* __restrict__ bias, float* __restrict__ C,
    int M, int N, int K) {
  __shared__ unsigned char lds[2 * BUFS];  // 68 KiB

  const int tid = threadIdx.x;
  const int l   = tid & 63;
  const int wid = tid >> 6;
  const int wm  = wid >> 2;  // 0..1
  const int wn  = wid & 3;   // 0..3

  const int nwg = gridDim.x;       // multiple of 8
  const int bid = blockIdx.x;
  const int swz = (bid & 7) * (nwg >> 3) + (bid >> 3);
  const int nbn = N / BN;
  const int bm  = swz / nbn;
  const int bn  = swz % nbn;

  const int KC = K >> 5;  // 16B-chunks per row within a panel

  f32x16 acc[4][2] = {};

#define STAGE(BUFO, KT)                                                        \
  do {                                                                         \
    const int cl = wid & 3;                                                    \
    const int rg2 = (wid >> 2) << 1;                                           \
    const size_t abase = ((size_t)bm * KC + (size_t)(KT) * 4 + cl) * 4096;     \
    const size_t bbase = ((size_t)bn * KC + (size_t)(KT) * 4 + cl) * 4096;     \
    _Pragma("unroll") for (int i = 0; i < 2; ++i) {                            \
      __builtin_amdgcn_global_load_lds(                                        \
          GLOBAL_CPTR(Aq + abase + (rg2 + i) * 1024 + (l << 4)),               \
          LDS_PTR(lds + (BUFO) + cl * 4096 + (rg2 + i) * 1024), 16, 0, 0);     \
      __builtin_amdgcn_global_load_lds(                                        \
          GLOBAL_CPTR(Bq + bbase + (rg2 + i) * 1024 + (l << 4)),               \
          LDS_PTR(lds + (BUFO) + 16384 + cl * 4096 + (rg2 + i) * 1024),        \
          16, 0, 0);                                                           \
    }                                                                          \
    if (wid < 4) {                                                             \
      __builtin_amdgcn_global_load_lds(                                        \
          GLOBAL_CPTR(Asc + ((size_t)bm * KC + (size_t)(KT) * 4 + wid) * 256   \
                      + (l << 2)),                                             \
          LDS_PTR(lds + (BUFO) + 32768 + wid * 256), 4, 0, 0);                 \
    } else {                                                                   \
      __builtin_amdgcn_global_load_lds(                                        \
          GLOBAL_CPTR(Bsc + ((size_t)bn * KC + (size_t)(KT) * 4 + (wid - 4))   \
                      * 256 + (l << 2)),                                       \
          LDS_PTR(lds + (BUFO) + 33792 + (wid - 4) * 256), 4, 0, 0);           \
    }                                                                          \
  } while (0)

#define KTILE(BUFO)                                                            \
  do {                                                                         \
    const i32x4 z4 = {0, 0, 0, 0};                                             \
    _Pragma("unroll") for (int ks = 0; ks < 2; ++ks) {                         \
      const int cofs = (ks << 13) + ((l & 32) << 7); /* (2ks+(l>>5))*4096 */   \
      i32x8 a8[4], b8[2];                                                      \
      int sa[4], sb[2];                                                        \
      _Pragma("unroll") for (int mb = 0; mb < 4; ++mb)                         \
        a8[mb] = __builtin_shufflevector(                                      \
            *(const i32x4*)(lds + (BUFO) + cofs +                              \
                            (((wm << 7) + (mb << 5) + (l & 31)) << 4)),        \
            z4, 0, 1, 2, 3, 4, 5, 6, 7);                                       \
      _Pragma("unroll") for (int nb = 0; nb < 2; ++nb)                         \
        b8[nb] = __builtin_shufflevector(                                      \
            *(const i32x4*)(lds + (BUFO) + 16384 + cofs +                      \
                            (((wn << 6) + (nb << 5) + (l & 31)) << 4)),        \
            z4, 0, 1, 2, 3, 4, 5, 6, 7);                                       \
      const int av = *(const int*)(lds + (BUFO) + 32768 + (cofs >> 4) +        \
                                   ((l & 31) << 3) + (wm << 2));               \
      const int bv = *(const ushort*)(lds + (BUFO) + 33792 + (cofs >> 4) +     \
                                      ((l & 31) << 3) + (wn << 1));            \
      _Pragma("unroll") for (int mb = 0; mb < 4; ++mb)                         \
        sa[mb] = (int)((unsigned)((av >> (mb << 3)) & 255) * 0x01010101u);     \
      _Pragma("unroll") for (int nb = 0; nb < 2; ++nb)                         \
        sb[nb] = (int)((unsigned)((bv >> (nb << 3)) & 255) * 0x01010101u);     \
      _Pragma("unroll") for (int mb = 0; mb < 4; ++mb)                         \
        _Pragma("unroll") for (int nb = 0; nb < 2; ++nb)                       \
          acc[mb][nb] = __builtin_amdgcn_mfma_scale_f32_32x32x64_f8f6f4(       \
              a8[mb], b8[nb], acc[mb][nb], 4, 4, 0, sa[mb], 0, sb[nb]);        \
    }                                                                          \
  } while (0)

  // prologue: tile0 -> buf0
  STAGE(0, 0);
  asm volatile("s_waitcnt vmcnt(0)" ::: "memory");
  __builtin_amdgcn_s_barrier();
  asm volatile("" ::: "memory");

  const int NKT = K >> 7;  // 128-wide K-tiles
  for (int t = 0; t < NKT; ++t) {
    const int tn = (t + 1 < NKT) ? (t + 1) : t;  // clamp -> dead buffer
    const int bufC = (t & 1) ? BUFS : 0;
    const int bufN = (t & 1) ? 0 : BUFS;
    STAGE(bufN, tn);       // issued first: full MFMA window to land
    KTILE(bufC);
    asm volatile("s_waitcnt vmcnt(0)" ::: "memory");  // 5 loads, pre-satisfied
    __builtin_amdgcn_s_barrier();
    asm volatile("" ::: "memory");
  }

  // epilogue: 32x32 C/D layout: col=lane&31, row=(reg&3)+8*(reg>>2)+4*(l>>5)
  const int colb = bn * BN + wn * 64 + (l & 31);
  const int rowb = bm * BM + wm * 128 + ((l >> 5) << 2);
  const float bv0 = bias[colb];
  const float bv1 = bias[colb + 32];
#pragma unroll
  for (int mb = 0; mb < 4; ++mb) {
#pragma unroll
    for (int nb = 0; nb < 2; ++nb) {
      const float bv = nb ? bv1 : bv0;
      const int col = colb + nb * 32;
#pragma unroll
      for (int r = 0; r < 16; ++r) {
        const int row = rowb + mb * 32 + ((r >> 2) << 3) + (r & 3);
        C[(size_t)row * N + col] = acc[mb][nb][r] + bv;
      }
    }
  }
}

// ---------------------------------------------------------------------------
extern "C" void kernel_launch(void* const* d_in, const int* in_sizes, int n_in,
                              void* d_out, int out_size, void* d_ws, size_t ws_size,
                              hipStream_t stream) {
  const float* x    = (const float*)d_in[0];  // [B,S,K] = [M,K]
  const float* w    = (const float*)d_in[1];  // [N,K]
  const float* bias = (const float*)d_in[2];  // [N]
  float* out = (float*)d_out;

  const int N = in_sizes[2];
  const int K = in_sizes[1] / N;
  const int M = (int)((long long)in_sizes[0] / K);
  const int kshift = __builtin_ctz(K);

  unsigned char* xq  = (unsigned char*)d_ws;               // M*K/2
  unsigned char* wq  = xq + ((size_t)M * K >> 1);          // N*K/2
  unsigned char* xsc = wq + ((size_t)N * K >> 1);          // M*K/32
  unsigned char* wsc = xsc + ((size_t)M * K >> 5);         // N*K/32

  const int CQ = (K >> 5) >> 2;  // chunk-quads per row

  mxfp4_quant_pack_kernel<<<dim3((unsigned)((M >> 6) * CQ)), dim3(256), 0,
                            stream>>>(x, xq, xsc, kshift);
  mxfp4_quant_pack_kernel<<<dim3((unsigned)((N >> 6) * CQ)), dim3(256), 0,
                            stream>>>(w, wq, wsc, kshift);

  dim3 grid((M / BM) * (N / BN));
  mxfp_gemm_kernel<<<grid, dim3(NTHR), 0, stream>>>(xq, xsc, wq, wsc, bias, out,
                                                    M, N, K);
}

// Round 12
// 136.778 us; speedup vs baseline: 1.2526x; 1.0247x over previous
//
#include <hip/hip_runtime.h>
#include <hip/hip_bf16.h>

typedef __attribute__((ext_vector_type(4))) int i32x4;
typedef __attribute__((ext_vector_type(8))) int i32x8;
typedef __attribute__((ext_vector_type(16))) float f32x16;

#define GLOBAL_CPTR(x) ((__attribute__((address_space(1))) const void*)(x))
#define LDS_PTR(x)     ((__attribute__((address_space(3))) void*)(x))

// ---------------------------------------------------------------------------
// MXFP4 quantize (merged: x and w in ONE launch; grid split on blockIdx).
// Block = 64 rows x 128 k. Phase 1: coalesced float4 loads into padded LDS.
// Phase 2: one thread = one full 32-elem MXFP block; quads write full 64B
// lines. Layout: chunk=(row>>8)*(K/32)+(k>>5); data=chunk*4096+(row&255)*16;
// scale byte = chunk*256+(row&31)*8+((row>>5)&7).
// ---------------------------------------------------------------------------
__global__ __launch_bounds__(256) void mxfp4_quant_pack_kernel(
    const float* __restrict__ xin, unsigned char* __restrict__ xq,
    unsigned char* __restrict__ xsc, const float* __restrict__ win,
    unsigned char* __restrict__ wq, unsigned char* __restrict__ wsc,
    int kshift, int gx) {
  const int KC = 1 << (kshift - 5);   // 32-elem chunks per row
  const int CQ = KC >> 2;             // chunk-quads per row (pow2)
  const int bid0 = blockIdx.x;
  const float* in;
  unsigned char* outq;
  unsigned char* outsc;
  int bid;
  if (bid0 < gx) { in = xin; outq = xq; outsc = xsc; bid = bid0; }
  else           { in = win; outq = wq; outsc = wsc; bid = bid0 - gx; }

  const int cq  = bid & (CQ - 1);     // 128-k span
  const int R   = (bid >> (kshift - 7)) << 6;  // 64-row block base
  const int t   = threadIdx.x;

  __shared__ float sf[64 * 132];      // 33 KB, row stride 132 (pad 4)

  // phase 1: load 64 rows x 128 floats, contiguous bursts
  const float* base = in + ((size_t)R << kshift) + (cq << 7);
#pragma unroll
  for (int i = 0; i < 8; ++i) {
    const int g   = i * 256 + t;      // float4 index 0..2047
    const int row = g >> 5;           // 32 float4 per row
    const int c4  = g & 31;
    float4 v = *reinterpret_cast<const float4*>(
        base + ((size_t)row << kshift) + (c4 << 2));
    *reinterpret_cast<float4*>(sf + row * 132 + (c4 << 2)) = v;
  }
  __syncthreads();

  // phase 2: thread -> (row rl, chunk kc); quads share kc with 4 consecutive
  // rows (full-line stores).
  const int rl = (t & 3) + ((t >> 4) << 2);   // 0..63
  const int kc = (t >> 2) & 3;                // 0..3
  const float* src = sf + rl * 132 + (kc << 5);
  float v[32];
#pragma unroll
  for (int i = 0; i < 8; ++i)
    *reinterpret_cast<float4*>(v + 4 * i) =
        *reinterpret_cast<const float4*>(src + 4 * i);

  float am = 0.f;
#pragma unroll
  for (int j = 0; j < 32; ++j) am = fmaxf(am, fabsf(v[j]));

  const float safe = am > 0.f ? am : 1.f;
  const int se = ilogbf(safe) - 2;    // floor(log2(amax)) - E2M1_EMAX
  const float inv = ldexpf(1.f, -se);

  unsigned int packs[4] = {0, 0, 0, 0};
#pragma unroll
  for (int j = 0; j < 32; ++j) {
    const float val = v[j] * inv;              // exact (power-of-2)
    const float av = fabsf(val);
    const float avc = fmaxf(av, 9.765625e-4f); // 2^-10 floor
    int ee = (int)((__float_as_uint(avc) >> 23) & 0xFF) - 127;
    ee = ee < 0 ? 0 : (ee > 2 ? 2 : ee);
    const float istep = __uint_as_float((unsigned)(128 - ee) << 23); // 2^(1-ee)
    const int m = (int)rintf(av * istep);      // exact small int
    unsigned int c = (unsigned)(m + (ee << 1));
    c = c > 7u ? 7u : c;
    c |= (__float_as_uint(val) >> 28) & 8u;    // sign bit -> bit3
    packs[j >> 3] |= c << (4 * (j & 7));
  }

  const int row = R + rl;
  const size_t chunk = (size_t)(row >> 8) * KC + (cq << 2) + kc;
  *reinterpret_cast<uint4*>(outq + chunk * 4096 + (size_t)(row & 255) * 16) =
      make_uint4(packs[0], packs[1], packs[2], packs[3]);
  outsc[chunk * 256 + (row & 31) * 8 + ((row >> 5) & 7)] =
      (unsigned char)(se + 127);
}

// ---------------------------------------------------------------------------
// MX-FP4 scaled GEMM: C[M][N] = dequant(A)*dequant(B)^T + bias
// via v_mfma_scale_f32_32x32x64_f8f6f4 (FMT=4 E2M1, E8M0 block scales).
// 256x256 tile, BK=128, 8 waves (2Mx4N, 128x64 out/wave).
// R12 (= R11 intent, opsel args as LITERAL constants via macro expansion):
//  (1) scale via OPSEL byte-select immediates (raw scale word passed to the
//      intrinsic; removes 24 bfe/mul VALU instrs per wave per K-tile);
//  (2) QUAD-buffered LDS (136KB), ONE barrier per TWO K-tiles: waves on a
//      SIMD drift out of phase inside the 6600-cyc window so one wave's
//      MFMAs overlap the other's LDS reads.
// LDS buffer: [A data 16KB][B data 16KB][A sc 1KB][B sc 1KB] stride 34816.
// ---------------------------------------------------------------------------
#define BM 256
#define BN 256
#define NTHR 512
#define BUFS 34816

__global__ __launch_bounds__(NTHR, 2) void mxfp_gemm_kernel(
    const unsigned char* __restrict__ Aq, const unsigned char* __restrict__ Asc,
    const unsigned char* __restrict__ Bq, const unsigned char* __restrict__ Bsc,
    const float* __restrict__ bias, float* __restrict__ C,
    int M, int N, int K) {
  __shared__ unsigned char lds[4 * BUFS];  // 136 KiB

  const int tid = threadIdx.x;
  const int l   = tid & 63;
  const int wid = tid >> 6;
  const int wm  = wid >> 2;  // 0..1
  const int wn  = wid & 3;   // 0..3

  const int nwg = gridDim.x;       // multiple of 8
  const int bid = blockIdx.x;
  const int swz = (bid & 7) * (nwg >> 3) + (bid >> 3);
  const int nbn = N / BN;
  const int bm  = swz / nbn;
  const int bn  = swz % nbn;

  const int KC = K >> 5;  // 16B-chunks per row within a panel

  f32x16 acc[4][2] = {};

#define STAGE(BUFO, KT)                                                        \
  do {                                                                         \
    const int cl = wid & 3;                                                    \
    const int rg2 = (wid >> 2) << 1;                                           \
    const size_t abase = ((size_t)bm * KC + (size_t)(KT) * 4 + cl) * 4096;     \
    const size_t bbase = ((size_t)bn * KC + (size_t)(KT) * 4 + cl) * 4096;     \
    _Pragma("unroll") for (int i = 0; i < 2; ++i) {                            \
      __builtin_amdgcn_global_load_lds(                                        \
          GLOBAL_CPTR(Aq + abase + (rg2 + i) * 1024 + (l << 4)),               \
          LDS_PTR(lds + (BUFO) + cl * 4096 + (rg2 + i) * 1024), 16, 0, 0);     \
      __builtin_amdgcn_global_load_lds(                                        \
          GLOBAL_CPTR(Bq + bbase + (rg2 + i) * 1024 + (l << 4)),               \
          LDS_PTR(lds + (BUFO) + 16384 + cl * 4096 + (rg2 + i) * 1024),        \
          16, 0, 0);                                                           \
    }                                                                          \
    if (wid < 4) {                                                             \
      __builtin_amdgcn_global_load_lds(                                        \
          GLOBAL_CPTR(Asc + ((size_t)bm * KC + (size_t)(KT) * 4 + wid) * 256   \
                      + (l << 2)),                                             \
          LDS_PTR(lds + (BUFO) + 32768 + wid * 256), 4, 0, 0);                 \
    } else {                                                                   \
      __builtin_amdgcn_global_load_lds(                                        \
          GLOBAL_CPTR(Bsc + ((size_t)bn * KC + (size_t)(KT) * 4 + (wid - 4))   \
                      * 256 + (l << 2)),                                       \
          LDS_PTR(lds + (BUFO) + 33792 + (wid - 4) * 256), 4, 0, 0);           \
    }                                                                          \
  } while (0)

// one MFMA with literal opsel byte indices (required: constant integer args)
#define MFMA1(MB, NB, AV, BV)                                                  \
  acc[MB][NB] = __builtin_amdgcn_mfma_scale_f32_32x32x64_f8f6f4(               \
      a8[MB], b8[NB], acc[MB][NB], 4, 4, MB, AV, NB, BV)

// compute one K-tile: 12 frag reads + 2 scale reads; scales consumed via
// opsel byte-select immediates (no bfe/mul replication).
#define KTILE(BUFO)                                                            \
  do {                                                                         \
    const i32x4 z4 = {0, 0, 0, 0};                                             \
    _Pragma("unroll") for (int ks = 0; ks < 2; ++ks) {                         \
      const int cofs = (ks << 13) + ((l & 32) << 7); /* (2ks+(l>>5))*4096 */   \
      i32x8 a8[4], b8[2];                                                      \
      _Pragma("unroll") for (int mb = 0; mb < 4; ++mb)                         \
        a8[mb] = __builtin_shufflevector(                                      \
            *(const i32x4*)(lds + (BUFO) + cofs +                              \
                            (((wm << 7) + (mb << 5) + (l & 31)) << 4)),        \
            z4, 0, 1, 2, 3, 4, 5, 6, 7);                                       \
      _Pragma("unroll") for (int nb = 0; nb < 2; ++nb)                         \
        b8[nb] = __builtin_shufflevector(                                      \
            *(const i32x4*)(lds + (BUFO) + 16384 + cofs +                      \
                            (((wn << 6) + (nb << 5) + (l & 31)) << 4)),        \
            z4, 0, 1, 2, 3, 4, 5, 6, 7);                                       \
      const int av = *(const int*)(lds + (BUFO) + 32768 + (cofs >> 4) +        \
                                   ((l & 31) << 3) + (wm << 2));               \
      const int bv = *(const ushort*)(lds + (BUFO) + 33792 + (cofs >> 4) +     \
                                      ((l & 31) << 3) + (wn << 1));            \
      MFMA1(0, 0, av, bv); MFMA1(0, 1, av, bv);                                \
      MFMA1(1, 0, av, bv); MFMA1(1, 1, av, bv);                                \
      MFMA1(2, 0, av, bv); MFMA1(2, 1, av, bv);                                \
      MFMA1(3, 0, av, bv); MFMA1(3, 1, av, bv);                                \
    }                                                                          \
  } while (0)

  // prologue: tiles 0,1 -> pair A (buf0, buf1)
  STAGE(0, 0);
  STAGE(BUFS, 1);
  asm volatile("s_waitcnt vmcnt(0)" ::: "memory");
  __builtin_amdgcn_s_barrier();
  asm volatile("" ::: "memory");

  const int NKT = K >> 7;  // 128-wide K-tiles (even)
  for (int w = 0; w < (NKT >> 1); ++w) {
    const int t = w << 1;
    const int c = (w & 1) ? 2 * BUFS : 0;        // compute pair base
    const int p = (w & 1) ? 0 : 2 * BUFS;        // stage pair base
    const int t2 = (t + 2 < NKT) ? (t + 2) : (NKT - 1);  // clamp -> dead
    const int t3 = (t + 3 < NKT) ? (t + 3) : (NKT - 1);  // clamp -> dead
    STAGE(p, t2);
    KTILE(c);
    STAGE(p + BUFS, t3);
    KTILE(c + BUFS);
    // one drain + one barrier per TWO K-tiles; both stage groups issued
    // >=3300 cyc earlier -> pre-satisfied.
    asm volatile("s_waitcnt vmcnt(0)" ::: "memory");
    __builtin_amdgcn_s_barrier();
    asm volatile("" ::: "memory");
  }

  // epilogue: 32x32 C/D layout: col=lane&31, row=(reg&3)+8*(reg>>2)+4*(l>>5)
  const int colb = bn * BN + wn * 64 + (l & 31);
  const int rowb = bm * BM + wm * 128 + ((l >> 5) << 2);
  const float bv0 = bias[colb];
  const float bv1 = bias[colb + 32];
#pragma unroll
  for (int mb = 0; mb < 4; ++mb) {
#pragma unroll
    for (int nb = 0; nb < 2; ++nb) {
      const float bv = nb ? bv1 : bv0;
      const int col = colb + nb * 32;
#pragma unroll
      for (int r = 0; r < 16; ++r) {
        const int row = rowb + mb * 32 + ((r >> 2) << 3) + (r & 3);
        C[(size_t)row * N + col] = acc[mb][nb][r] + bv;
      }
    }
  }
}

// ---------------------------------------------------------------------------
extern "C" void kernel_launch(void* const* d_in, const int* in_sizes, int n_in,
                              void* d_out, int out_size, void* d_ws, size_t ws_size,
                              hipStream_t stream) {
  const float* x    = (const float*)d_in[0];  // [B,S,K] = [M,K]
  const float* w    = (const float*)d_in[1];  // [N,K]
  const float* bias = (const float*)d_in[2];  // [N]
  float* out = (float*)d_out;

  const int N = in_sizes[2];
  const int K = in_sizes[1] / N;
  const int M = (int)((long long)in_sizes[0] / K);
  const int kshift = __builtin_ctz(K);

  unsigned char* xq  = (unsigned char*)d_ws;               // M*K/2
  unsigned char* wq  = xq + ((size_t)M * K >> 1);          // N*K/2
  unsigned char* xsc = wq + ((size_t)N * K >> 1);          // M*K/32
  unsigned char* wsc = xsc + ((size_t)M * K >> 5);         // N*K/32

  const int CQ = (K >> 5) >> 2;  // chunk-quads per row
  const int gx = (M >> 6) * CQ;
  const int gw = (N >> 6) * CQ;

  mxfp4_quant_pack_kernel<<<dim3((unsigned)(gx + gw)), dim3(256), 0, stream>>>(
      x, xq, xsc, w, wq, wsc, kshift, gx);

  dim3 grid((M / BM) * (N / BN));
  mxfp_gemm_kernel<<<grid, dim3(NTHR), 0, stream>>>(xq, xsc, wq, wsc, bias, out,
                                                    M, N, K);
}